// Round 7
// baseline (191.294 us; speedup 1.0000x reference)
//
#include <hip/hip_runtime.h>

#define N_ 2048
#define S_ 16
#define D_ 128
#define H_ 8
#define EPS_ 1e-5f

typedef unsigned short ushortT;
typedef unsigned int uint32;
typedef __attribute__((ext_vector_type(8))) short short8;
typedef __attribute__((ext_vector_type(8))) unsigned short ushort8;
typedef __attribute__((ext_vector_type(4))) float f32x4;
typedef __attribute__((ext_vector_type(4))) unsigned int uint4v;
typedef __attribute__((ext_vector_type(8))) float float8;

__device__ __forceinline__ ushortT f2bf(float f) {
  union { float f; uint32 u; } c; c.f = f;
  uint32 u = c.u;
  u = (u + 0x7FFFu + ((u >> 16) & 1u)) >> 16;  // RNE
  return (ushortT)u;
}
__device__ __forceinline__ float bf2f(ushortT b) {
  union { uint32 u; float f; } c; c.u = ((uint32)b) << 16;
  return c.f;
}

// ---------------------------------------------------------------------------
// K0: per-(n,d) column: stable-descending ranks over S=16.
// enc -> enc_sw fragment order (wave-contiguous 128B runs).
// diff -> diff_sw glds-linear swizzled tiles [bt128][s][pp][1024 q][8e],
//      q = row*8 + (c8 ^ (row&7)).
// ---------------------------------------------------------------------------
__global__ __launch_bounds__(256) void k_prep(const float* __restrict__ x,
                                              ushortT* __restrict__ enc_sw,
                                              ushortT* __restrict__ diff_sw) {
  int g = blockIdx.x * 256 + threadIdx.x;  // N*D = 262144 threads
  int n = g >> 7, d = g & 127;
  const float* xp = x + (size_t)n * (S_ * D_) + d;
  float v[S_];
#pragma unroll
  for (int s = 0; s < S_; ++s) v[s] = xp[s * D_];
  int r[S_];
#pragma unroll
  for (int i = 0; i < S_; ++i) {
    int ri = 0;
#pragma unroll
    for (int j = 0; j < S_; ++j)
      ri += ((v[j] > v[i]) || (v[j] == v[i] && j < i)) ? 1 : 0;
    r[i] = ri;
  }
  float xs[S_ + 1];
#pragma unroll
  for (int s = 0; s < S_; ++s) {
    float acc = 0.f;
#pragma unroll
    for (int i = 0; i < S_; ++i) acc += (r[i] == s) ? v[i] : 0.f;
    xs[s] = acc;
  }
  xs[S_] = 0.f;
  // enc_sw addressing (fragment order, wave-contiguous)
  int btq = n >> 7, row = n & 127;
  int wv = row >> 5, ii = (row >> 4) & 1, l15n = row & 15;
  int kkm = d >> 5, lgm = (d >> 3) & 3, em = d & 7;
  int off_nd = (((kkm * 2 + ii) * 64) + (l15n * 4 + lgm)) * 8 + em;
  // diff_sw addressing (glds-linear swizzled)
  int pp = d >> 6, c8p = (d >> 3) & 7, ee = d & 7;
  int q = row * 8 + (c8p ^ (row & 7));
#pragma unroll
  for (int s = 0; s < S_; ++s) {
    uint32 mm = 0;
#pragma unroll
    for (int i = 0; i < S_; ++i) mm |= (r[i] <= s) ? (1u << i) : 0u;
    enc_sw[(size_t)((btq * 16 + s) * 4 + wv) * 4096 + off_nd] =
        f2bf((float)mm * (1.f / 65536.f));
    size_t idx = ((((size_t)(btq * 16 + s) * 2 + pp) * 1024) + q) * 8 + ee;
    diff_sw[idx] = f2bf(xs[s] - xs[s + 1]);
  }
}

// ---------------------------------------------------------------------------
// K0b: merged weight casts, 512 threads/block. All global stores lane-linear.
// ---------------------------------------------------------------------------
__global__ __launch_bounds__(512) void k_castW(const float* __restrict__ Wi,
                                               const float* __restrict__ Wj,
                                               ushortT* __restrict__ Wit_sw,
                                               ushortT* __restrict__ Wjt_sw) {
  __shared__ ushortT tile[128 * 136];
  int bx = blockIdx.x;
  int t = threadIdx.x;
  if (bx < 128) {
    int hs = bx;
    const float* src = Wi + (size_t)hs * D_ * D_;
#pragma unroll 4
    for (int i = 0; i < 32; ++i) {
      int e = t + 512 * i;
      int dd = e >> 7, o = e & 127;
      tile[dd * 136 + o] = f2bf(src[e]);
    }
    __syncthreads();
    ushortT* dst = Wit_sw + (size_t)hs * 16384;
#pragma unroll
    for (int r8 = 0; r8 < 4; ++r8) {
      int qc = r8 * 512 + t;
      int o = qc >> 4;
      int cc = (qc & 15) ^ (o & 7);
      uint4v pk;
#pragma unroll
      for (int w = 0; w < 4; ++w) {
        int d0 = cc * 8 + w * 2;
        ushortT lo = tile[d0 * 136 + o];
        ushortT hi = tile[(d0 + 1) * 136 + o];
        pk[w] = (uint32)lo | ((uint32)hi << 16);
      }
      *(uint4v*)(dst + qc * 8) = pk;
    }
  } else {
    int hs = bx - 128;
    const float* src = Wj + (size_t)hs * 256 * D_;
    for (int half = 0; half < 2; ++half) {
      if (half) __syncthreads();
#pragma unroll 4
      for (int i = 0; i < 32; ++i) {
        int e = t + 512 * i;
        int dd = e >> 7, o = e & 127;
        tile[dd * 136 + o] = f2bf(src[half * 16384 + e]);
      }
      __syncthreads();
      ushortT* dstb = Wjt_sw + ((size_t)hs * 4 + half * 2) * 8192;
#pragma unroll
      for (int r8 = 0; r8 < 4; ++r8) {
        int cg = r8 * 512 + t;
        int pl = cg >> 10;
        int qc = cg & 1023;
        int o = qc >> 3;
        int c8 = (qc & 7) ^ (o & 7);
        int dl = pl * 64 + c8 * 8;
        uint4v pk;
#pragma unroll
        for (int w = 0; w < 4; ++w) {
          ushortT lo = tile[(dl + w * 2) * 136 + o];
          ushortT hi = tile[(dl + w * 2 + 1) * 136 + o];
          pk[w] = (uint32)lo | ((uint32)hi << 16);
        }
        *(uint4v*)(dstb + (size_t)pl * 8192 + qc * 8) = pk;
      }
    }
  }
}

// ---------------------------------------------------------------------------
// K1: se = enc @ Wi per (bt,s,h); sum/sumsq partials. (unchanged from r5/r6)
// ---------------------------------------------------------------------------
__global__ __launch_bounds__(256, 3) void k_gemm1(const ushortT* __restrict__ enc_sw,
                                                  const ushortT* __restrict__ Wit_sw,
                                                  ushortT* __restrict__ se,
                                                  float* __restrict__ ssum,
                                                  float* __restrict__ ssq) {
  int bt = blockIdx.x, s = blockIdx.y, h = blockIdx.z;
  __shared__ ushortT Bs[128 * 132];  // 33 KB
  int tid = threadIdx.x;
  int wave = tid >> 6, lane = tid & 63;
  int l15 = lane & 15, lg = lane >> 4;

  const ushortT* bsrc = Wit_sw + (size_t)(h * 16 + s) * 16384;
#pragma unroll
  for (int r8 = 0; r8 < 8; ++r8)
    __builtin_amdgcn_global_load_lds(
        (const __attribute__((address_space(1))) void*)(bsrc + (r8 * 256 + tid) * 8),
        (__attribute__((address_space(3))) void*)(Bs + (r8 * 256 + wave * 64) * 8),
        16, 0, 0);

  short8 afr[4][2];
  const ushortT* abase = enc_sw + ((size_t)(bt * 16 + s) * 4 + wave) * 4096;
#pragma unroll
  for (int kk = 0; kk < 4; ++kk)
#pragma unroll
    for (int i = 0; i < 2; ++i)
      afr[kk][i] = *(const short8*)(abase + (((kk * 2 + i) * 64) + (l15 * 4 + lg)) * 8);

  __syncthreads();

  f32x4 acc[2][8];
#pragma unroll
  for (int i = 0; i < 2; ++i)
#pragma unroll
    for (int j = 0; j < 8; ++j) acc[i][j] = (f32x4)(0.f);
#pragma unroll
  for (int kk = 0; kk < 4; ++kk) {
    int cc = kk * 4 + lg;
    short8 b[8];
#pragma unroll
    for (int j = 0; j < 8; ++j) {
      int row = j * 16 + l15;
      b[j] = *(const short8*)(Bs + (row * 16 + (cc ^ (row & 7))) * 8);
    }
#pragma unroll
    for (int i = 0; i < 2; ++i)
#pragma unroll
      for (int j = 0; j < 8; ++j)
        acc[i][j] = __builtin_amdgcn_mfma_f32_16x16x32_bf16(afr[kk][i], b[j], acc[i][j], 0, 0, 0);
  }
#pragma unroll
  for (int i = 0; i < 2; ++i)
#pragma unroll
    for (int rr = 0; rr < 4; ++rr) {
      int rloc = wave * 32 + i * 16 + lg * 4 + rr;
      int b_g = bt * 128 + rloc;
      float rs = 0.f, rq = 0.f;
#pragma unroll
      for (int j = 0; j < 8; ++j) {
        float val = acc[i][j][rr];
        rs += val; rq += val * val;
      }
#pragma unroll
      for (int m = 1; m <= 8; m <<= 1) {
        rs += __shfl_xor(rs, m);
        rq += __shfl_xor(rq, m);
      }
      if (l15 == 0) {
        ssum[((size_t)s * N_ + b_g) * H_ + h] = rs;
        ssq[((size_t)s * N_ + b_g) * H_ + h] = rq;
      }
    }
  __syncthreads();
#pragma unroll
  for (int i = 0; i < 2; ++i)
#pragma unroll
    for (int rr = 0; rr < 4; ++rr) {
      int row = wave * 32 + i * 16 + lg * 4 + rr;
      int sw = (row & 7) << 3;
#pragma unroll
      for (int j = 0; j < 8; ++j) {
        int o = j * 16 + l15;
        Bs[row * 132 + (o ^ sw)] = f2bf(acc[i][j][rr]);
      }
    }
  __syncthreads();
#pragma unroll
  for (int p = 0; p < 2; ++p) {
    int row = p * 64 + (tid >> 2);
    int sw = (row & 7) << 3;
    int b_g = bt * 128 + row;
    ushortT* dst = se + (((size_t)b_g * H_ + h) * S_ + s) * D_;
#pragma unroll
    for (int qq = 0; qq < 4; ++qq) {
      int o0 = (qq * 4 + (tid & 3)) * 8;
      *(uint4v*)(dst + o0) = *(const uint4v*)(Bs + row * 132 + (o0 ^ sw));
    }
  }
}

// ---------------------------------------------------------------------------
// K2: LN1 stats finalize -> (rstd, -mu*rstd) per (b,h)
// ---------------------------------------------------------------------------
__global__ __launch_bounds__(256) void k_finalize(const float* __restrict__ ssum,
                                                  const float* __restrict__ ssq,
                                                  float* __restrict__ mr) {
  int t = blockIdx.x * 256 + threadIdx.x;  // N*H = 16384
  float s1 = 0.f, s2 = 0.f;
#pragma unroll
  for (int s = 0; s < S_; ++s) {
    s1 += ssum[(size_t)s * (N_ * H_) + t];
    s2 += ssq[(size_t)s * (N_ * H_) + t];
  }
  float mu = s1 * (1.f / 2048.f);
  float var = s2 * (1.f / 2048.f) - mu * mu;
  float rstd = rsqrtf(var + EPS_);
  mr[t * 2] = rstd;
  mr[t * 2 + 1] = -mu * rstd;
}

// ---------------------------------------------------------------------------
// K3: out_part[sh] = sum over 4 s of [diff | act(LN1(se))] @ Wj[h,s]
// BM=64, grid (32,4,8)=1024 blocks (3/CU by LDS). T14 reg-staged pipeline:
// 4 rotating named reg sets, issue 3 chunks ahead; global->reg loads stay in
// flight across __syncthreads (no LDS-visibility drain); ds_write of chunk
// c+1 waits only its own 2-phase-old loads. One barrier per BK=64 chunk.
// Chunk c: s = s0 + (c>>2), part p=c&3: {diff-lo, diff-hi, se-lo, se-hi}.
// ---------------------------------------------------------------------------
__global__ __launch_bounds__(256, 3) void k_gemm2(const ushortT* __restrict__ diff_sw,
                                                  const ushortT* __restrict__ se,
                                                  const ushortT* __restrict__ Wjt_sw,
                                                  const float* __restrict__ mr,
                                                  const float* __restrict__ ln1w,
                                                  const float* __restrict__ ln1b,
                                                  const float* __restrict__ pa1,
                                                  float* __restrict__ outp) {
  int bt2 = blockIdx.x, sh = blockIdx.y, h = blockIdx.z;
  int s0 = sh * 4;
  __shared__ ushortT As[2][64 * 64];    // 2 x 8 KB
  __shared__ ushortT Bs[2][128 * 64];   // 2 x 16 KB
  int tid = threadIdx.x;
  int wave = tid >> 6, lane = tid & 63;
  int c8 = tid & 7, trow = tid >> 3;    // trow 0..31
  int swst = ((c8 ^ (trow & 7)) * 8);
  int l15 = lane & 15, lg = lane >> 4;
  int wm = wave >> 1, wn = wave & 1;
  float a1 = pa1[0];

  float rs_r[2], nm_r[2];
  uint32 aoff_s[2];
#pragma unroll
  for (int i = 0; i < 2; ++i) {
    int row = i * 32 + trow;
    int b_g = bt2 * 64 + row;
    rs_r[i] = mr[((size_t)b_g * H_ + h) * 2];
    nm_r[i] = mr[((size_t)b_g * H_ + h) * 2 + 1];
    aoff_s[i] = ((uint32)b_g * H_ + h) * (S_ * D_) + c8 * 8;
  }
  const ushortT* dbase = diff_sw + (size_t)(bt2 >> 1) * (S_ * 2 * 8192) + (bt2 & 1) * 4096;
  const ushortT* wbase = Wjt_sw + (size_t)(h * 16) * 4 * 8192 + wave * 512 + lane * 8;

  // 4 rotating reg sets (named; rule #20 static indexing)
  uint4v S0b0, S0b1, S0b2, S0b3, S0a0, S0a1;
  uint4v S1b0, S1b1, S1b2, S1b3, S1a0, S1a1;
  uint4v S2b0, S2b1, S2b2, S2b3, S2a0, S2a1;
  uint4v S3b0, S3b1, S3b2, S3b3, S3a0, S3a1;

#define ISSUE_B(P, SS, PP) do {                                               \
    const ushortT* bp_ = wbase + ((size_t)(SS) * 4 + (PP)) * 8192;            \
    P##b0 = *(const uint4v*)(bp_);                                            \
    P##b1 = *(const uint4v*)(bp_ + 2048);                                     \
    P##b2 = *(const uint4v*)(bp_ + 4096);                                     \
    P##b3 = *(const uint4v*)(bp_ + 6144);                                     \
  } while (0)

#define ISSUE_DIFF(P, SS, PP) do {                                            \
    ISSUE_B(P, SS, (PP));                                                     \
    const ushortT* ap_ = dbase + ((size_t)(SS) * 2 + (PP)) * 8192 + wave * 512 + lane * 8; \
    P##a0 = *(const uint4v*)(ap_);                                            \
    P##a1 = *(const uint4v*)(ap_ + 2048);                                     \
  } while (0)

#define ISSUE_SE(P, SS, HALF) do {                                            \
    ISSUE_B(P, SS, 2 + (HALF));                                               \
    P##a0 = *(const uint4v*)(se + aoff_s[0] + (SS) * D_ + (HALF) * 64);       \
    P##a1 = *(const uint4v*)(se + aoff_s[1] + (SS) * D_ + (HALF) * 64);       \
  } while (0)

#define WRITE_B(P, BUF) do {                                                  \
    ushortT* dp_ = Bs[BUF] + wave * 512 + lane * 8;                           \
    *(uint4v*)(dp_) = P##b0;                                                  \
    *(uint4v*)(dp_ + 2048) = P##b1;                                           \
    *(uint4v*)(dp_ + 4096) = P##b2;                                           \
    *(uint4v*)(dp_ + 6144) = P##b3;                                           \
  } while (0)

#define WRITE_DIFF(P, BUF) do {                                               \
    WRITE_B(P, BUF);                                                          \
    ushortT* ap_ = As[BUF] + wave * 512 + lane * 8;                           \
    *(uint4v*)(ap_) = P##a0;                                                  \
    *(uint4v*)(ap_ + 2048) = P##a1;                                           \
  } while (0)

#define WRITE_SE(P, BUF, SS, HALF) do {                                       \
    WRITE_B(P, BUF);                                                          \
    float8 w8 = *(const float8*)(ln1w + (SS) * D_ + (HALF) * 64 + c8 * 8);    \
    float8 b8 = *(const float8*)(ln1b + (SS) * D_ + (HALF) * 64 + c8 * 8);    \
    _Pragma("unroll")                                                         \
    for (int i_ = 0; i_ < 2; ++i_) {                                          \
      ushort8 va_ = (i_ == 0) ? *(ushort8*)&P##a0 : *(ushort8*)&P##a1;        \
      int row_ = i_ * 32 + trow;                                              \
      float y_[8];                                                            \
      _Pragma("unroll")                                                       \
      for (int e_ = 0; e_ < 8; ++e_) {                                        \
        float f_ = bf2f((ushortT)va_[e_]);                                    \
        float t_ = fmaf(f_, rs_r[i_], nm_r[i_]);                              \
        float v_ = fmaf(t_, w8[e_], b8[e_]);                                  \
        y_[e_] = fmaf(a1, fminf(v_, 0.f), fmaxf(v_, 0.f));                    \
      }                                                                       \
      uint4v pk_;                                                             \
      _Pragma("unroll")                                                       \
      for (int q_ = 0; q_ < 4; ++q_) {                                        \
        uint32 r_;                                                            \
        asm("v_cvt_pk_bf16_f32 %0, %1, %2" : "=v"(r_)                         \
            : "v"(y_[2 * q_]), "v"(y_[2 * q_ + 1]));                          \
        pk_[q_] = r_;                                                         \
      }                                                                       \
      *(uint4v*)(As[BUF] + row_ * 64 + swst) = pk_;                           \
    } } while (0)

  f32x4 acc[2][4];
#pragma unroll
  for (int i = 0; i < 2; ++i)
#pragma unroll
    for (int j = 0; j < 4; ++j) acc[i][j] = (f32x4)(0.f);

#define COMPUTE(XBUF) do {                                                    \
    _Pragma("unroll")                                                         \
    for (int kk = 0; kk < 2; ++kk) {                                          \
      int cc = kk * 4 + lg;                                                   \
      short8 a[2], b[4];                                                      \
      _Pragma("unroll")                                                       \
      for (int i = 0; i < 2; ++i) {                                           \
        int row = wm * 32 + i * 16 + l15;                                     \
        a[i] = *(const short8*)(As[XBUF] + row * 64 + ((cc ^ (row & 7)) * 8));\
      }                                                                       \
      _Pragma("unroll")                                                       \
      for (int j = 0; j < 4; ++j) {                                           \
        int row = wn * 64 + j * 16 + l15;                                     \
        b[j] = *(const short8*)(Bs[XBUF] + row * 64 + ((cc ^ (row & 7)) * 8));\
      }                                                                       \
      __builtin_amdgcn_s_setprio(1);                                          \
      _Pragma("unroll")                                                       \
      for (int i = 0; i < 2; ++i)                                             \
        _Pragma("unroll")                                                     \
        for (int j = 0; j < 4; ++j)                                           \
          acc[i][j] = __builtin_amdgcn_mfma_f32_16x16x32_bf16(a[i], b[j],     \
                                                              acc[i][j], 0, 0, 0); \
      __builtin_amdgcn_s_setprio(0);                                          \
    } } while (0)

  // prologue: issue chunks 0(p0),1(p1),2(p2 se-lo); write chunk0 -> buf0
  ISSUE_DIFF(S0, s0, 0);
  ISSUE_DIFF(S1, s0, 1);
  ISSUE_SE(S2, s0, 0);
  WRITE_DIFF(S0, 0);
  __syncthreads();

  for (int si = 0; si < 4; ++si) {
    int s = s0 + si;
    int sn = (si + 1 < 4) ? s + 1 : s0;  // wrapped issue/write is junk, never computed
    // j=0: compute c0(buf0); consume S1(diff-hi)->buf1; issue se-hi(s)->S3
    ISSUE_SE(S3, s, 1);
    WRITE_DIFF(S1, 1);
    COMPUTE(0);
    __syncthreads();
    // j=1: compute c1(buf1); consume S2(se-lo,transform)->buf0; issue diff-lo(sn)->S0
    ISSUE_DIFF(S0, sn, 0);
    WRITE_SE(S2, 0, s, 0);
    COMPUTE(1);
    __syncthreads();
    // j=2: compute c2(buf0); consume S3(se-hi,transform)->buf1; issue diff-hi(sn)->S1
    ISSUE_DIFF(S1, sn, 1);
    WRITE_SE(S3, 1, s, 1);
    COMPUTE(0);
    __syncthreads();
    // j=3: compute c3(buf1); consume S0(diff-lo of sn)->buf0; issue se-lo(sn)->S2
    ISSUE_SE(S2, sn, 0);
    WRITE_DIFF(S0, 0);
    COMPUTE(1);
    __syncthreads();
  }

#pragma unroll
  for (int i = 0; i < 2; ++i)
#pragma unroll
    for (int j = 0; j < 4; ++j)
#pragma unroll
      for (int rr = 0; rr < 4; ++rr) {
        int b_g = bt2 * 64 + wm * 32 + i * 16 + lg * 4 + rr;
        int o = wn * 64 + j * 16 + l15;
        outp[(((size_t)sh * N_ + b_g) * H_ + h) * D_ + o] = acc[i][j][rr];
      }
#undef ISSUE_B
#undef ISSUE_DIFF
#undef ISSUE_SE
#undef WRITE_B
#undef WRITE_DIFF
#undef WRITE_SE
#undef COMPUTE
}

// ---------------------------------------------------------------------------
// K4: combine 4 K-partials, LN2 over (H,D)=1024 per b, PReLU, f32 out
// ---------------------------------------------------------------------------
__global__ __launch_bounds__(256) void k_ln2(const float* __restrict__ outp,
                                             const float* __restrict__ ln2w,
                                             const float* __restrict__ ln2b,
                                             const float* __restrict__ pa2,
                                             float* __restrict__ out) {
  int b = blockIdx.x, t = threadIdx.x;
  __shared__ float red[8];
  __shared__ float stats[2];
  f32x4 v = (f32x4)(0.f);
#pragma unroll
  for (int p = 0; p < 4; ++p)
    v += *((const f32x4*)(outp + (size_t)p * (N_ * 1024) + (size_t)b * 1024) + t);
  float s1 = v[0] + v[1] + v[2] + v[3];
  float s2 = v[0] * v[0] + v[1] * v[1] + v[2] * v[2] + v[3] * v[3];
#pragma unroll
  for (int m = 1; m <= 32; m <<= 1) {
    s1 += __shfl_xor(s1, m);
    s2 += __shfl_xor(s2, m);
  }
  int wave = t >> 6, lane = t & 63;
  if (lane == 0) { red[wave] = s1; red[4 + wave] = s2; }
  __syncthreads();
  if (t == 0) {
    float S = red[0] + red[1] + red[2] + red[3];
    float Q = red[4] + red[5] + red[6] + red[7];
    float mu = S * (1.f / 1024.f);
    float var = Q * (1.f / 1024.f) - mu * mu;
    stats[0] = mu; stats[1] = rsqrtf(var + EPS_);
  }
  __syncthreads();
  float mu = stats[0], rstd = stats[1];
  float a2 = pa2[0];
  f32x4 wv = *((const f32x4*)ln2w + t);
  f32x4 bv = *((const f32x4*)ln2b + t);
  f32x4 r;
#pragma unroll
  for (int e = 0; e < 4; ++e) {
    float y = (v[e] - mu) * rstd * wv[e] + bv[e];
    r[e] = (y >= 0.f) ? y : a2 * y;
  }
  *((f32x4*)(out + (size_t)b * 1024) + t) = r;
}

// ---------------------------------------------------------------------------
extern "C" void kernel_launch(void* const* d_in, const int* in_sizes, int n_in,
                              void* d_out, int out_size, void* d_ws, size_t ws_size,
                              hipStream_t stream) {
  const float* x    = (const float*)d_in[0];
  const float* Wi   = (const float*)d_in[1];
  const float* Wj   = (const float*)d_in[2];
  const float* ln1w = (const float*)d_in[3];
  const float* ln1b = (const float*)d_in[4];
  const float* pa1  = (const float*)d_in[5];
  const float* ln2w = (const float*)d_in[6];
  const float* ln2b = (const float*)d_in[7];
  const float* pa2  = (const float*)d_in[8];
  char* ws = (char*)d_ws;
  // ws layout (no overlays; peak ~126 MB):
  //   [0,64M)      se       [64M,72M)    diff_sw   [72M,80M)   Wjt_sw
  //   [80M,112M)   outp(4)  [112M,120M)  enc_sw    [120M,124M) Wit_sw
  //   [124M,125M)  ssum     [125M,126M)  ssq       [126M,+128K) mr
  ushortT* se      = (ushortT*)(ws + 0);
  ushortT* diff_sw = (ushortT*)(ws + 67108864);
  ushortT* Wjt_sw  = (ushortT*)(ws + 75497472);
  float*   outp    = (float*)(ws + 83886080);
  ushortT* enc_sw  = (ushortT*)(ws + 117440512);
  ushortT* Wit_sw  = (ushortT*)(ws + 125829120);
  float*   ssum    = (float*)(ws + 130023424);
  float*   ssq     = (float*)(ws + 131072000);
  float*   mr      = (float*)(ws + 132120576);
  float*   out     = (float*)d_out;

  hipLaunchKernelGGL(k_prep, dim3(1024), dim3(256), 0, stream, x, enc_sw, diff_sw);
  hipLaunchKernelGGL(k_castW, dim3(256), dim3(512), 0, stream, Wi, Wj, Wit_sw, Wjt_sw);
  hipLaunchKernelGGL(k_gemm1, dim3(16, 16, 8), dim3(256), 0, stream, enc_sw, Wit_sw, se, ssum, ssq);
  hipLaunchKernelGGL(k_finalize, dim3(64), dim3(256), 0, stream, ssum, ssq, mr);
  hipLaunchKernelGGL(k_gemm2, dim3(32, 4, 8), dim3(256), 0, stream, diff_sw, se, Wjt_sw, mr,
                     ln1w, ln1b, pa1, outp);
  hipLaunchKernelGGL(k_ln2, dim3(2048), dim3(256), 0, stream, outp, ln2w, ln2b, pa2, out);
}

// Round 8
// 189.073 us; speedup vs baseline: 1.0117x; 1.0117x over previous
//
#include <hip/hip_runtime.h>

#define N_ 2048
#define S_ 16
#define D_ 128
#define H_ 8
#define EPS_ 1e-5f

typedef unsigned short ushortT;
typedef unsigned int uint32;
typedef __attribute__((ext_vector_type(8))) short short8;
typedef __attribute__((ext_vector_type(8))) unsigned short ushort8;
typedef __attribute__((ext_vector_type(4))) float f32x4;
typedef __attribute__((ext_vector_type(4))) unsigned int uint4v;
typedef __attribute__((ext_vector_type(8))) float float8;

__device__ __forceinline__ ushortT f2bf(float f) {
  union { float f; uint32 u; } c; c.f = f;
  uint32 u = c.u;
  u = (u + 0x7FFFu + ((u >> 16) & 1u)) >> 16;  // RNE
  return (ushortT)u;
}
__device__ __forceinline__ float bf2f(ushortT b) {
  union { uint32 u; float f; } c; c.u = ((uint32)b) << 16;
  return c.f;
}

// ---------------------------------------------------------------------------
// K0: per-(n,d) column: stable-descending ranks over S=16.
// enc -> enc_sw fragment order (wave-contiguous 128B runs).
// diff -> diff_sw glds-linear swizzled tiles [bt128][s][pp][1024 q][8e],
//      q = row*8 + (c8 ^ (row&7)).
// ---------------------------------------------------------------------------
__global__ __launch_bounds__(256) void k_prep(const float* __restrict__ x,
                                              ushortT* __restrict__ enc_sw,
                                              ushortT* __restrict__ diff_sw) {
  int g = blockIdx.x * 256 + threadIdx.x;  // N*D = 262144 threads
  int n = g >> 7, d = g & 127;
  const float* xp = x + (size_t)n * (S_ * D_) + d;
  float v[S_];
#pragma unroll
  for (int s = 0; s < S_; ++s) v[s] = xp[s * D_];
  int r[S_];
#pragma unroll
  for (int i = 0; i < S_; ++i) {
    int ri = 0;
#pragma unroll
    for (int j = 0; j < S_; ++j)
      ri += ((v[j] > v[i]) || (v[j] == v[i] && j < i)) ? 1 : 0;
    r[i] = ri;
  }
  float xs[S_ + 1];
#pragma unroll
  for (int s = 0; s < S_; ++s) {
    float acc = 0.f;
#pragma unroll
    for (int i = 0; i < S_; ++i) acc += (r[i] == s) ? v[i] : 0.f;
    xs[s] = acc;
  }
  xs[S_] = 0.f;
  // enc_sw addressing (fragment order, wave-contiguous)
  int btq = n >> 7, row = n & 127;
  int wv = row >> 5, ii = (row >> 4) & 1, l15n = row & 15;
  int kkm = d >> 5, lgm = (d >> 3) & 3, em = d & 7;
  int off_nd = (((kkm * 2 + ii) * 64) + (l15n * 4 + lgm)) * 8 + em;
  // diff_sw addressing (glds-linear swizzled)
  int pp = d >> 6, c8p = (d >> 3) & 7, ee = d & 7;
  int q = row * 8 + (c8p ^ (row & 7));
#pragma unroll
  for (int s = 0; s < S_; ++s) {
    uint32 mm = 0;
#pragma unroll
    for (int i = 0; i < S_; ++i) mm |= (r[i] <= s) ? (1u << i) : 0u;
    enc_sw[(size_t)((btq * 16 + s) * 4 + wv) * 4096 + off_nd] =
        f2bf((float)mm * (1.f / 65536.f));
    size_t idx = ((((size_t)(btq * 16 + s) * 2 + pp) * 1024) + q) * 8 + ee;
    diff_sw[idx] = f2bf(xs[s] - xs[s + 1]);
  }
}

// ---------------------------------------------------------------------------
// K0b: merged weight casts, 512 threads/block. All global stores lane-linear.
// ---------------------------------------------------------------------------
__global__ __launch_bounds__(512) void k_castW(const float* __restrict__ Wi,
                                               const float* __restrict__ Wj,
                                               ushortT* __restrict__ Wit_sw,
                                               ushortT* __restrict__ Wjt_sw) {
  __shared__ ushortT tile[128 * 136];
  int bx = blockIdx.x;
  int t = threadIdx.x;
  if (bx < 128) {
    int hs = bx;
    const float* src = Wi + (size_t)hs * D_ * D_;
#pragma unroll 4
    for (int i = 0; i < 32; ++i) {
      int e = t + 512 * i;
      int dd = e >> 7, o = e & 127;
      tile[dd * 136 + o] = f2bf(src[e]);
    }
    __syncthreads();
    ushortT* dst = Wit_sw + (size_t)hs * 16384;
#pragma unroll
    for (int r8 = 0; r8 < 4; ++r8) {
      int qc = r8 * 512 + t;
      int o = qc >> 4;
      int cc = (qc & 15) ^ (o & 7);
      uint4v pk;
#pragma unroll
      for (int w = 0; w < 4; ++w) {
        int d0 = cc * 8 + w * 2;
        ushortT lo = tile[d0 * 136 + o];
        ushortT hi = tile[(d0 + 1) * 136 + o];
        pk[w] = (uint32)lo | ((uint32)hi << 16);
      }
      *(uint4v*)(dst + qc * 8) = pk;
    }
  } else {
    int hs = bx - 128;
    const float* src = Wj + (size_t)hs * 256 * D_;
    for (int half = 0; half < 2; ++half) {
      if (half) __syncthreads();
#pragma unroll 4
      for (int i = 0; i < 32; ++i) {
        int e = t + 512 * i;
        int dd = e >> 7, o = e & 127;
        tile[dd * 136 + o] = f2bf(src[half * 16384 + e]);
      }
      __syncthreads();
      ushortT* dstb = Wjt_sw + ((size_t)hs * 4 + half * 2) * 8192;
#pragma unroll
      for (int r8 = 0; r8 < 4; ++r8) {
        int cg = r8 * 512 + t;
        int pl = cg >> 10;
        int qc = cg & 1023;
        int o = qc >> 3;
        int c8 = (qc & 7) ^ (o & 7);
        int dl = pl * 64 + c8 * 8;
        uint4v pk;
#pragma unroll
        for (int w = 0; w < 4; ++w) {
          ushortT lo = tile[(dl + w * 2) * 136 + o];
          ushortT hi = tile[(dl + w * 2 + 1) * 136 + o];
          pk[w] = (uint32)lo | ((uint32)hi << 16);
        }
        *(uint4v*)(dstb + (size_t)pl * 8192 + qc * 8) = pk;
      }
    }
  }
}

// ---------------------------------------------------------------------------
// K1: se = enc @ Wi per (bt,s,h); sum/sumsq partials. (unchanged)
// ---------------------------------------------------------------------------
__global__ __launch_bounds__(256, 3) void k_gemm1(const ushortT* __restrict__ enc_sw,
                                                  const ushortT* __restrict__ Wit_sw,
                                                  ushortT* __restrict__ se,
                                                  float* __restrict__ ssum,
                                                  float* __restrict__ ssq) {
  int bt = blockIdx.x, s = blockIdx.y, h = blockIdx.z;
  __shared__ ushortT Bs[128 * 132];  // 33 KB
  int tid = threadIdx.x;
  int wave = tid >> 6, lane = tid & 63;
  int l15 = lane & 15, lg = lane >> 4;

  const ushortT* bsrc = Wit_sw + (size_t)(h * 16 + s) * 16384;
#pragma unroll
  for (int r8 = 0; r8 < 8; ++r8)
    __builtin_amdgcn_global_load_lds(
        (const __attribute__((address_space(1))) void*)(bsrc + (r8 * 256 + tid) * 8),
        (__attribute__((address_space(3))) void*)(Bs + (r8 * 256 + wave * 64) * 8),
        16, 0, 0);

  short8 afr[4][2];
  const ushortT* abase = enc_sw + ((size_t)(bt * 16 + s) * 4 + wave) * 4096;
#pragma unroll
  for (int kk = 0; kk < 4; ++kk)
#pragma unroll
    for (int i = 0; i < 2; ++i)
      afr[kk][i] = *(const short8*)(abase + (((kk * 2 + i) * 64) + (l15 * 4 + lg)) * 8);

  __syncthreads();

  f32x4 acc[2][8];
#pragma unroll
  for (int i = 0; i < 2; ++i)
#pragma unroll
    for (int j = 0; j < 8; ++j) acc[i][j] = (f32x4)(0.f);
#pragma unroll
  for (int kk = 0; kk < 4; ++kk) {
    int cc = kk * 4 + lg;
    short8 b[8];
#pragma unroll
    for (int j = 0; j < 8; ++j) {
      int row = j * 16 + l15;
      b[j] = *(const short8*)(Bs + (row * 16 + (cc ^ (row & 7))) * 8);
    }
#pragma unroll
    for (int i = 0; i < 2; ++i)
#pragma unroll
      for (int j = 0; j < 8; ++j)
        acc[i][j] = __builtin_amdgcn_mfma_f32_16x16x32_bf16(afr[kk][i], b[j], acc[i][j], 0, 0, 0);
  }
#pragma unroll
  for (int i = 0; i < 2; ++i)
#pragma unroll
    for (int rr = 0; rr < 4; ++rr) {
      int rloc = wave * 32 + i * 16 + lg * 4 + rr;
      int b_g = bt * 128 + rloc;
      float rs = 0.f, rq = 0.f;
#pragma unroll
      for (int j = 0; j < 8; ++j) {
        float val = acc[i][j][rr];
        rs += val; rq += val * val;
      }
#pragma unroll
      for (int m = 1; m <= 8; m <<= 1) {
        rs += __shfl_xor(rs, m);
        rq += __shfl_xor(rq, m);
      }
      if (l15 == 0) {
        ssum[((size_t)s * N_ + b_g) * H_ + h] = rs;
        ssq[((size_t)s * N_ + b_g) * H_ + h] = rq;
      }
    }
  __syncthreads();
#pragma unroll
  for (int i = 0; i < 2; ++i)
#pragma unroll
    for (int rr = 0; rr < 4; ++rr) {
      int row = wave * 32 + i * 16 + lg * 4 + rr;
      int sw = (row & 7) << 3;
#pragma unroll
      for (int j = 0; j < 8; ++j) {
        int o = j * 16 + l15;
        Bs[row * 132 + (o ^ sw)] = f2bf(acc[i][j][rr]);
      }
    }
  __syncthreads();
#pragma unroll
  for (int p = 0; p < 2; ++p) {
    int row = p * 64 + (tid >> 2);
    int sw = (row & 7) << 3;
    int b_g = bt * 128 + row;
    ushortT* dst = se + (((size_t)b_g * H_ + h) * S_ + s) * D_;
#pragma unroll
    for (int qq = 0; qq < 4; ++qq) {
      int o0 = (qq * 4 + (tid & 3)) * 8;
      *(uint4v*)(dst + o0) = *(const uint4v*)(Bs + row * 132 + (o0 ^ sw));
    }
  }
}

// ---------------------------------------------------------------------------
// K2: LN1 stats finalize -> (rstd, -mu*rstd) per (b,h)
// ---------------------------------------------------------------------------
__global__ __launch_bounds__(256) void k_finalize(const float* __restrict__ ssum,
                                                  const float* __restrict__ ssq,
                                                  float* __restrict__ mr) {
  int t = blockIdx.x * 256 + threadIdx.x;  // N*H = 16384
  float s1 = 0.f, s2 = 0.f;
#pragma unroll
  for (int s = 0; s < S_; ++s) {
    s1 += ssum[(size_t)s * (N_ * H_) + t];
    s2 += ssq[(size_t)s * (N_ * H_) + t];
  }
  float mu = s1 * (1.f / 2048.f);
  float var = s2 * (1.f / 2048.f) - mu * mu;
  float rstd = rsqrtf(var + EPS_);
  mr[t * 2] = rstd;
  mr[t * 2 + 1] = -mu * rstd;
}

// ---------------------------------------------------------------------------
// K3: out_part[sh] = sum over 4 s of [diff | act(LN1(se))] @ Wj[h,s]
// Round-6 glds dbuf structure; nsplit=4; grid (h=8, bt2=32, sh=4) with h
// FASTEST so the 8 co-resident same-(bt2,sh) blocks share diff/se in L2.
// BM=64, LDS 48KB (3 blocks/CU), one __syncthreads per BK=64 chunk.
// ---------------------------------------------------------------------------
#define GLDS_B(DST, SRC) do {                                                 \
    const ushortT* sp_ = (SRC) + wave * 512 + lane * 8;                       \
    ushortT* dp_ = (DST) + wave * 512;                                        \
    _Pragma("unroll")                                                         \
    for (int i_ = 0; i_ < 4; ++i_)                                            \
      __builtin_amdgcn_global_load_lds(                                       \
          (const __attribute__((address_space(1))) void*)(sp_ + i_ * 2048),   \
          (__attribute__((address_space(3))) void*)(dp_ + i_ * 2048),         \
          16, 0, 0);                                                          \
  } while (0)

#define GLDS_A(DST, SRC) do {                                                 \
    const ushortT* sp_ = (SRC) + wave * 512 + lane * 8;                       \
    ushortT* dp_ = (DST) + wave * 512;                                        \
    _Pragma("unroll")                                                         \
    for (int i_ = 0; i_ < 2; ++i_)                                            \
      __builtin_amdgcn_global_load_lds(                                       \
          (const __attribute__((address_space(1))) void*)(sp_ + i_ * 2048),   \
          (__attribute__((address_space(3))) void*)(dp_ + i_ * 2048),         \
          16, 0, 0);                                                          \
  } while (0)

__global__ __launch_bounds__(256, 3) void k_gemm2(const ushortT* __restrict__ diff_sw,
                                                  const ushortT* __restrict__ se,
                                                  const ushortT* __restrict__ Wjt_sw,
                                                  const float* __restrict__ mr,
                                                  const float* __restrict__ ln1w,
                                                  const float* __restrict__ ln1b,
                                                  const float* __restrict__ pa1,
                                                  float* __restrict__ outp) {
  int h = blockIdx.x, bt2 = blockIdx.y, sh = blockIdx.z;
  int s0 = sh * 4;
  __shared__ ushortT As[2][64 * 64];    // 2 x 8 KB
  __shared__ ushortT Bs[2][128 * 64];   // 2 x 16 KB
  int tid = threadIdx.x;
  int wave = tid >> 6, lane = tid & 63;
  int c8 = tid & 7, trow = tid >> 3;    // trow 0..31
  int swst = ((c8 ^ (trow & 7)) * 8);
  int l15 = lane & 15, lg = lane >> 4;
  int wm = wave >> 1, wn = wave & 1;
  float a1 = pa1[0];

  float rs_r[2], nm_r[2];
  uint32 aoff_s[2];
#pragma unroll
  for (int i = 0; i < 2; ++i) {
    int row = i * 32 + trow;
    int b_g = bt2 * 64 + row;
    rs_r[i] = mr[((size_t)b_g * H_ + h) * 2];
    nm_r[i] = mr[((size_t)b_g * H_ + h) * 2 + 1];
    aoff_s[i] = ((uint32)b_g * H_ + h) * (S_ * D_) + c8 * 8;
  }
  const ushortT* dbase = diff_sw + (size_t)(bt2 >> 1) * (S_ * 2 * 8192) + (bt2 & 1) * 4096;
  ushort8 raL[2], raH[2];
  f32x4 acc[2][4];
#pragma unroll
  for (int i = 0; i < 2; ++i)
#pragma unroll
    for (int j = 0; j < 4; ++j) acc[i][j] = (f32x4)(0.f);

#define COMPUTE(XBUF) do {                                                    \
    _Pragma("unroll")                                                         \
    for (int kk = 0; kk < 2; ++kk) {                                          \
      int cc = kk * 4 + lg;                                                   \
      short8 a[2], b[4];                                                      \
      _Pragma("unroll")                                                       \
      for (int i = 0; i < 2; ++i) {                                           \
        int row = wm * 32 + i * 16 + l15;                                     \
        a[i] = *(const short8*)(As[XBUF] + row * 64 + ((cc ^ (row & 7)) * 8));\
      }                                                                       \
      _Pragma("unroll")                                                       \
      for (int j = 0; j < 4; ++j) {                                           \
        int row = wn * 64 + j * 16 + l15;                                     \
        b[j] = *(const short8*)(Bs[XBUF] + row * 64 + ((cc ^ (row & 7)) * 8));\
      }                                                                       \
      __builtin_amdgcn_s_setprio(1);                                          \
      _Pragma("unroll")                                                       \
      for (int i = 0; i < 2; ++i)                                             \
        _Pragma("unroll")                                                     \
        for (int j = 0; j < 4; ++j)                                           \
          acc[i][j] = __builtin_amdgcn_mfma_f32_16x16x32_bf16(a[i], b[j],     \
                                                              acc[i][j], 0, 0, 0); \
      __builtin_amdgcn_s_setprio(0);                                          \
    } } while (0)

#define TRANSFORM_WRITE(RA, NXBUF, SS, HALF) do {                             \
    float8 w8 = *(const float8*)(ln1w + (SS) * D_ + (HALF) * 64 + c8 * 8);    \
    float8 b8 = *(const float8*)(ln1b + (SS) * D_ + (HALF) * 64 + c8 * 8);    \
    _Pragma("unroll")                                                         \
    for (int i = 0; i < 2; ++i) {                                             \
      int row = i * 32 + trow;                                                \
      float y[8];                                                             \
      _Pragma("unroll")                                                       \
      for (int e = 0; e < 8; ++e) {                                           \
        float f = bf2f((ushortT)RA[i][e]);                                    \
        float tt = fmaf(f, rs_r[i], nm_r[i]);                                 \
        float vv = fmaf(tt, w8[e], b8[e]);                                    \
        y[e] = fmaf(a1, fminf(vv, 0.f), fmaxf(vv, 0.f));                      \
      }                                                                       \
      uint4v pk;                                                              \
      _Pragma("unroll")                                                       \
      for (int q = 0; q < 4; ++q) {                                           \
        uint32 rpk;                                                           \
        asm("v_cvt_pk_bf16_f32 %0, %1, %2" : "=v"(rpk)                        \
            : "v"(y[2 * q]), "v"(y[2 * q + 1]));                              \
        pk[q] = rpk;                                                          \
      }                                                                       \
      *(uint4v*)(As[NXBUF] + row * 64 + swst) = pk;                           \
    } } while (0)

  // prologue: chunk (s0, diff-lo) into buf0
  GLDS_A(As[0], dbase + ((size_t)s0 * 2 + 0) * 8192);
  GLDS_B(Bs[0], Wjt_sw + ((size_t)(h * 16 + s0) * 4 + 0) * 8192);
  __syncthreads();

  for (int si = 0; si < 4; ++si) {
    int s = s0 + si;
    int sn = (si + 1 < 4) ? s + 1 : s0;  // wrapped prefetch never computed
    // phase 0: compute (s,diff-lo) buf0; stage (s,diff-hi)->buf1; load se-lo
#pragma unroll
    for (int i = 0; i < 2; ++i)
      raL[i] = *(const ushort8*)(se + aoff_s[i] + s * D_);
    GLDS_A(As[1], dbase + ((size_t)s * 2 + 1) * 8192);
    GLDS_B(Bs[1], Wjt_sw + ((size_t)(h * 16 + s) * 4 + 1) * 8192);
    COMPUTE(0);
    __syncthreads();
    // phase 1: compute (s,diff-hi) buf1; se-lo -> buf0; load se-hi
#pragma unroll
    for (int i = 0; i < 2; ++i)
      raH[i] = *(const ushort8*)(se + aoff_s[i] + s * D_ + 64);
    TRANSFORM_WRITE(raL, 0, s, 0);
    GLDS_B(Bs[0], Wjt_sw + ((size_t)(h * 16 + s) * 4 + 2) * 8192);
    COMPUTE(1);
    __syncthreads();
    // phase 2: compute (s,se-lo) buf0; se-hi -> buf1
    TRANSFORM_WRITE(raH, 1, s, 1);
    GLDS_B(Bs[1], Wjt_sw + ((size_t)(h * 16 + s) * 4 + 3) * 8192);
    COMPUTE(0);
    __syncthreads();
    // phase 3: compute (s,se-hi) buf1; stage (sn,diff-lo)->buf0
    GLDS_A(As[0], dbase + ((size_t)sn * 2 + 0) * 8192);
    GLDS_B(Bs[0], Wjt_sw + ((size_t)(h * 16 + sn) * 4 + 0) * 8192);
    COMPUTE(1);
    __syncthreads();
  }

#pragma unroll
  for (int i = 0; i < 2; ++i)
#pragma unroll
    for (int j = 0; j < 4; ++j)
#pragma unroll
      for (int rr = 0; rr < 4; ++rr) {
        int b_g = bt2 * 64 + wm * 32 + i * 16 + lg * 4 + rr;
        int o = wn * 64 + j * 16 + l15;
        outp[(((size_t)sh * N_ + b_g) * H_ + h) * D_ + o] = acc[i][j][rr];
      }
#undef COMPUTE
#undef TRANSFORM_WRITE
}

// ---------------------------------------------------------------------------
// K4: combine 4 K-partials, LN2 over (H,D)=1024 per b, PReLU, f32 out
// ---------------------------------------------------------------------------
__global__ __launch_bounds__(256) void k_ln2(const float* __restrict__ outp,
                                             const float* __restrict__ ln2w,
                                             const float* __restrict__ ln2b,
                                             const float* __restrict__ pa2,
                                             float* __restrict__ out) {
  int b = blockIdx.x, t = threadIdx.x;
  __shared__ float red[8];
  __shared__ float stats[2];
  f32x4 v = (f32x4)(0.f);
#pragma unroll
  for (int p = 0; p < 4; ++p)
    v += *((const f32x4*)(outp + (size_t)p * (N_ * 1024) + (size_t)b * 1024) + t);
  float s1 = v[0] + v[1] + v[2] + v[3];
  float s2 = v[0] * v[0] + v[1] * v[1] + v[2] * v[2] + v[3] * v[3];
#pragma unroll
  for (int m = 1; m <= 32; m <<= 1) {
    s1 += __shfl_xor(s1, m);
    s2 += __shfl_xor(s2, m);
  }
  int wave = t >> 6, lane = t & 63;
  if (lane == 0) { red[wave] = s1; red[4 + wave] = s2; }
  __syncthreads();
  if (t == 0) {
    float S = red[0] + red[1] + red[2] + red[3];
    float Q = red[4] + red[5] + red[6] + red[7];
    float mu = S * (1.f / 1024.f);
    float var = Q * (1.f / 1024.f) - mu * mu;
    stats[0] = mu; stats[1] = rsqrtf(var + EPS_);
  }
  __syncthreads();
  float mu = stats[0], rstd = stats[1];
  float a2 = pa2[0];
  f32x4 wv = *((const f32x4*)ln2w + t);
  f32x4 bv = *((const f32x4*)ln2b + t);
  f32x4 r;
#pragma unroll
  for (int e = 0; e < 4; ++e) {
    float y = (v[e] - mu) * rstd * wv[e] + bv[e];
    r[e] = (y >= 0.f) ? y : a2 * y;
  }
  *((f32x4*)(out + (size_t)b * 1024) + t) = r;
}

// ---------------------------------------------------------------------------
extern "C" void kernel_launch(void* const* d_in, const int* in_sizes, int n_in,
                              void* d_out, int out_size, void* d_ws, size_t ws_size,
                              hipStream_t stream) {
  const float* x    = (const float*)d_in[0];
  const float* Wi   = (const float*)d_in[1];
  const float* Wj   = (const float*)d_in[2];
  const float* ln1w = (const float*)d_in[3];
  const float* ln1b = (const float*)d_in[4];
  const float* pa1  = (const float*)d_in[5];
  const float* ln2w = (const float*)d_in[6];
  const float* ln2b = (const float*)d_in[7];
  const float* pa2  = (const float*)d_in[8];
  char* ws = (char*)d_ws;
  // ws layout (no overlays; peak ~126 MB, ws is 256 MB):
  //   [0,64M)      se       [64M,72M)    diff_sw   [72M,80M)   Wjt_sw
  //   [80M,112M)   outp(4)  [112M,120M)  enc_sw    [120M,124M) Wit_sw
  //   [124M,125M)  ssum     [125M,126M)  ssq       [126M,+128K) mr
  ushortT* se      = (ushortT*)(ws + 0);
  ushortT* diff_sw = (ushortT*)(ws + 67108864);
  ushortT* Wjt_sw  = (ushortT*)(ws + 75497472);
  float*   outp    = (float*)(ws + 83886080);
  ushortT* enc_sw  = (ushortT*)(ws + 117440512);
  ushortT* Wit_sw  = (ushortT*)(ws + 125829120);
  float*   ssum    = (float*)(ws + 130023424);
  float*   ssq     = (float*)(ws + 131072000);
  float*   mr      = (float*)(ws + 132120576);
  float*   out     = (float*)d_out;

  hipLaunchKernelGGL(k_prep, dim3(1024), dim3(256), 0, stream, x, enc_sw, diff_sw);
  hipLaunchKernelGGL(k_castW, dim3(256), dim3(512), 0, stream, Wi, Wj, Wit_sw, Wjt_sw);
  hipLaunchKernelGGL(k_gemm1, dim3(16, 16, 8), dim3(256), 0, stream, enc_sw, Wit_sw, se, ssum, ssq);
  hipLaunchKernelGGL(k_finalize, dim3(64), dim3(256), 0, stream, ssum, ssq, mr);
  hipLaunchKernelGGL(k_gemm2, dim3(8, 32, 4), dim3(256), 0, stream, diff_sw, se, Wjt_sw, mr,
                     ln1w, ln1b, pa1, outp);
  hipLaunchKernelGGL(k_ln2, dim3(2048), dim3(256), 0, stream, outp, ln2w, ln2b, pa2, out);
}